// Round 9
// baseline (601.818 us; speedup 1.0000x reference)
//
#include <hip/hip_runtime.h>

#define B_ 8
#define CQ_ 256
#define CKV_ 512
#define N_ 4096
#define DQK_ 32

typedef __bf16 bf16;
typedef __bf16 bf16x4 __attribute__((ext_vector_type(4)));
typedef __bf16 bf16x8 __attribute__((ext_vector_type(8)));
typedef float f32x4 __attribute__((ext_vector_type(4)));

// ---------------- weight convert fp32 -> bf16 ----------------
__global__ void k_convert_w(const float* __restrict__ Wq, const float* __restrict__ Wk,
                            const float* __restrict__ Wv,
                            bf16* __restrict__ wq, bf16* __restrict__ wk, bf16* __restrict__ wv) {
    int i = blockIdx.x * 256 + threadIdx.x;
    if (i < 8192) wq[i] = (bf16)Wq[i];
    else if (i < 24576) wk[i - 8192] = (bf16)Wk[i - 8192];
    else if (i < 155648) wv[i - 24576] = (bf16)Wv[i - 24576];
}

// ---------------- fused: bilinear resize 32x32->64x64 (in LDS) + k-proj + v-proj ----------------
__global__ __launch_bounds__(256) void k_resize_projkv(const float* __restrict__ kv,   // [B][512][32][32]
                                                       const bf16* __restrict__ Wk,    // [32][512]
                                                       const float* __restrict__ bk,   // [32]
                                                       const bf16* __restrict__ Wv,    // [256][512]
                                                       const float* __restrict__ bv,   // [256]
                                                       bf16* __restrict__ kTb,         // [B][N][32]
                                                       bf16* __restrict__ vbuf) {      // [B][256][N]
    __shared__ float r0[128][33];
    __shared__ float r1[128][33];
    __shared__ bf16 kvt[64][136];   // [xo][u], row 272B (16B-aligned)
    const int yo = blockIdx.x;
    const int b  = blockIdx.y;
    const int tid = threadIdx.x;
    int ty = yo >> 1;
    int y0, y1; float wy0, wy1;
    if ((yo & 1) == 0) { y0 = ty > 0 ? ty - 1 : 0; y1 = ty; wy0 = 0.25f; wy1 = 0.75f; }
    else               { y0 = ty; y1 = ty < 31 ? ty + 1 : 31; wy0 = 0.75f; wy1 = 0.25f; }
    const int w = tid >> 6, lane = tid & 63;
    const int l16 = lane & 15, quad = lane >> 4;
    const int ct = w & 1;     // K-proj d-tile
    const int jp = w >> 1;    // K-proj j-pair
    const int u_loc = tid & 127, xo2 = tid >> 7;

    f32x4 acck[2];
    acck[0] = (f32x4){0.f, 0.f, 0.f, 0.f}; acck[1] = (f32x4){0.f, 0.f, 0.f, 0.f};
    f32x4 accv[4][4];
    for (int i = 0; i < 4; ++i) for (int j = 0; j < 4; ++j) accv[i][j] = (f32x4){0.f, 0.f, 0.f, 0.f};

    for (int uc = 0; uc < CKV_; uc += 128) {
        __syncthreads();   // prev chunk's MFMA reads done before restaging
        for (int i = 0; i < 16; ++i) {
            int idx = tid + i * 256;
            int u = idx >> 5, x = idx & 31;
            const float* src = kv + ((size_t)b * CKV_ + uc + u) * 1024 + x;
            r0[u][x] = src[y0 * 32];
            r1[u][x] = src[y1 * 32];
        }
        __syncthreads();
        for (int i = 0; i < 32; ++i) {
            int xo = xo2 + i * 2;
            int tx = xo >> 1;
            int xa, xb; float wxa, wxb;
            if ((xo & 1) == 0) { xa = tx > 0 ? tx - 1 : 0; xb = tx; wxa = 0.25f; wxb = 0.75f; }
            else               { xa = tx; xb = tx < 31 ? tx + 1 : 31; wxa = 0.75f; wxb = 0.25f; }
            float v0 = wxa * r0[u_loc][xa] + wxb * r0[u_loc][xb];
            float v1 = wxa * r1[u_loc][xa] + wxb * r1[u_loc][xb];
            kvt[xo][u_loc] = (bf16)(wy0 * v0 + wy1 * v1);
        }
        __syncthreads();
        for (int ks = 0; ks < 4; ++ks) {
            bf16x8 bfv[4];
            for (int j = 0; j < 4; ++j)
                bfv[j] = *(const bf16x8*)&kvt[j * 16 + l16][ks * 32 + quad * 8];
            bf16x8 afk = *(const bf16x8*)(Wk + (size_t)(ct * 16 + l16) * CKV_ + uc + ks * 32 + quad * 8);
            acck[0] = __builtin_amdgcn_mfma_f32_16x16x32_bf16(afk, bfv[jp * 2 + 0], acck[0], 0, 0, 0);
            acck[1] = __builtin_amdgcn_mfma_f32_16x16x32_bf16(afk, bfv[jp * 2 + 1], acck[1], 0, 0, 0);
            for (int i = 0; i < 4; ++i) {
                bf16x8 afv = *(const bf16x8*)(Wv + (size_t)((w * 4 + i) * 16 + l16) * CKV_ + uc + ks * 32 + quad * 8);
                for (int j = 0; j < 4; ++j)
                    accv[i][j] = __builtin_amdgcn_mfma_f32_16x16x32_bf16(afv, bfv[j], accv[i][j], 0, 0, 0);
            }
        }
    }
    const int m0 = yo * 64;
    for (int jj = 0; jj < 2; ++jj)
        for (int r = 0; r < 4; ++r) {
            int d = ct * 16 + quad * 4 + r;
            int m = m0 + (jp * 2 + jj) * 16 + l16;
            kTb[((size_t)b * N_ + m) * DQK_ + d] = (bf16)(acck[jj][r] + bk[d]);
        }
    for (int i = 0; i < 4; ++i)
        for (int r = 0; r < 4; ++r) {
            int c = w * 64 + i * 16 + quad * 4 + r;
            float bvs = bv[c];
            for (int j = 0; j < 4; ++j) {
                int m = m0 + j * 16 + l16;
                vbuf[((size_t)b * CQ_ + c) * N_ + m] = (bf16)(accv[i][j][r] + bvs);
            }
        }
}

// ---------------- fused: transpose query tile to LDS + q projection ----------------
// Output pre-scaled by log2(e) so flash uses exp2.
__global__ __launch_bounds__(256) void k_proj_q_fused(const float* __restrict__ query,
                                                      const bf16* __restrict__ W,     // [32][256]
                                                      const float* __restrict__ bias, // [32]
                                                      bf16* __restrict__ qTb) {       // [B][N][32]
    __shared__ bf16 tile[64][264];
    const int n0 = blockIdx.x * 64;
    const int b  = blockIdx.y;
    const int tid = threadIdx.x;
    const int xi = tid & 15, c0 = tid >> 4;
    for (int pass = 0; pass < 16; ++pass) {
        int c = c0 + pass * 16;
        const float4 v = *(const float4*)(query + ((size_t)b * CQ_ + c) * N_ + n0 + xi * 4);
        tile[xi * 4 + 0][c] = (bf16)v.x;
        tile[xi * 4 + 1][c] = (bf16)v.y;
        tile[xi * 4 + 2][c] = (bf16)v.z;
        tile[xi * 4 + 3][c] = (bf16)v.w;
    }
    __syncthreads();
    const int w = tid >> 6, lane = tid & 63;
    const int l16 = lane & 15, quad = lane >> 4;
    const int ct = w & 1, nh = w >> 1;
    f32x4 acc[2];
    acc[0] = (f32x4){0.f, 0.f, 0.f, 0.f}; acc[1] = (f32x4){0.f, 0.f, 0.f, 0.f};
    const bf16* aptr = W + (ct * 16 + l16) * CQ_ + quad * 8;
#pragma unroll
    for (int ks = 0; ks < 8; ++ks) {
        bf16x8 af = *(const bf16x8*)(aptr + ks * 32);
        for (int j = 0; j < 2; ++j) {
            bf16x8 bfv = *(const bf16x8*)&tile[nh * 32 + j * 16 + l16][ks * 32 + quad * 8];
            acc[j] = __builtin_amdgcn_mfma_f32_16x16x32_bf16(af, bfv, acc[j], 0, 0, 0);
        }
    }
    const float LOG2E = 1.4426950408889634f;
    for (int j = 0; j < 2; ++j)
        for (int r = 0; r < 4; ++r) {
            int d = ct * 16 + quad * 4 + r;
            int n = n0 + nh * 32 + j * 16 + l16;
            qTb[((size_t)b * N_ + n) * DQK_ + d] = (bf16)((acc[j][r] + bias[d]) * LOG2E);
        }
}

// ---------------- flash attention: split-K (z=2), cross-wave P, 1 barrier/iter ----------------
__global__ __launch_bounds__(256, 4) void k_flash(const bf16* __restrict__ qT,   // [B][N][32] (pre-scaled)
                                                  const bf16* __restrict__ kT,   // [B][N][32]
                                                  const bf16* __restrict__ vv,   // [B][256][N]
                                                  bf16* __restrict__ opart,      // [2][B][CQ][N]
                                                  float* __restrict__ lpart) {   // [2][B][N]
    __shared__ bf16 P[2][64][72];
    const int b  = blockIdx.x;
    const int n0 = blockIdx.y * 64;
    const int z  = blockIdx.z;
    const int mbase = z * (N_ / 2);
    const int tid = threadIdx.x;
    const int w = tid >> 6, lane = tid & 63;
    const int l16 = lane & 15, quad = lane >> 4;
    const int swz = (l16 & 3) ^ ((l16 >> 3) << 1);

    bf16x8 qfrag = *(const bf16x8*)(qT + ((size_t)b * N_ + n0 + w * 16 + l16) * DQK_ + quad * 8);

    const bf16 one = (bf16)1.0f;
    const bf16x8 ones = {one, one, one, one, one, one, one, one};
    const f32x4 zed = {0.f, 0.f, 0.f, 0.f};

    f32x4 acc[4][4];
    for (int i = 0; i < 4; ++i) for (int j = 0; j < 4; ++j) acc[i][j] = zed;
    f32x4 accl[4];
    for (int j = 0; j < 4; ++j) accl[j] = zed;

    const bf16* kbase = kT + (size_t)b * N_ * DQK_;
    const bf16* vbase = vv + ((size_t)b * CQ_ + w * 64) * N_;

    // preamble: S(first tile) -> P buf 0
    for (int im = 0; im < 4; ++im) {
        bf16x8 kf = *(const bf16x8*)(kbase + (size_t)(mbase + im * 16 + l16) * DQK_ + quad * 8);
        f32x4 s = __builtin_amdgcn_mfma_f32_16x16x32_bf16(kf, qfrag, zed, 0, 0, 0);
        bf16x4 pk;
        for (int r = 0; r < 4; ++r) pk[r] = (bf16)__builtin_amdgcn_exp2f(s[r]);
        *(bf16x4*)&P[0][w * 16 + l16][((im ^ swz) << 4) + quad * 4] = pk;
    }

    for (int mt = 0; mt < 32; ++mt) {
        __syncthreads();
        const int m0 = mbase + mt * 64;
        bf16 (* __restrict__ Pb)[72] = P[mt & 1];
        bf16x8 pf[2][4];
        for (int ks = 0; ks < 2; ++ks)
            for (int j = 0; j < 4; ++j)
                pf[ks][j] = *(const bf16x8*)&Pb[j * 16 + l16]
                                [((((ks << 1) | (quad >> 1)) ^ swz) << 4) + ((quad & 1) << 3)];
        bf16x8 vf[2][4];
        for (int ks = 0; ks < 2; ++ks)
            for (int i = 0; i < 4; ++i)
                vf[ks][i] = *(const bf16x8*)(vbase + (size_t)(i * 16 + l16) * N_ + m0 + ks * 32 + quad * 8);
        if (mt < 31) {
            const int m1 = m0 + 64;
            bf16 (* __restrict__ Pn)[72] = P[(mt + 1) & 1];
            for (int im = 0; im < 4; ++im) {
                bf16x8 kf = *(const bf16x8*)(kbase + (size_t)(m1 + im * 16 + l16) * DQK_ + quad * 8);
                f32x4 s = __builtin_amdgcn_mfma_f32_16x16x32_bf16(kf, qfrag, zed, 0, 0, 0);
                bf16x4 pk;
                for (int r = 0; r < 4; ++r) pk[r] = (bf16)__builtin_amdgcn_exp2f(s[r]);
                *(bf16x4*)&Pn[w * 16 + l16][((im ^ swz) << 4) + quad * 4] = pk;
            }
        }
        for (int ks = 0; ks < 2; ++ks)
            for (int j = 0; j < 4; ++j) {
                accl[j] = __builtin_amdgcn_mfma_f32_16x16x32_bf16(ones, pf[ks][j], accl[j], 0, 0, 0);
                for (int i = 0; i < 4; ++i)
                    acc[i][j] = __builtin_amdgcn_mfma_f32_16x16x32_bf16(vf[ks][i], pf[ks][j], acc[i][j], 0, 0, 0);
            }
    }

    // store partials (unnormalized)
    if (quad == 0)
        for (int j = 0; j < 4; ++j)
            lpart[((size_t)z * B_ + b) * N_ + n0 + j * 16 + l16] = accl[j][0];
    bf16* ob = opart + (size_t)z * B_ * CQ_ * N_;
    for (int i = 0; i < 4; ++i)
        for (int r = 0; r < 4; ++r) {
            int c = w * 64 + i * 16 + quad * 4 + r;
            for (int j = 0; j < 4; ++j) {
                int n = n0 + j * 16 + l16;
                ob[((size_t)b * CQ_ + c) * N_ + n] = (bf16)acc[i][j][r];
            }
        }
}

// ---------------- combine split-K halves + gamma*O/l + query ----------------
__global__ __launch_bounds__(256) void k_combine(const bf16* __restrict__ opart,
                                                 const float* __restrict__ lpart,
                                                 const float* __restrict__ query,
                                                 const float* __restrict__ gamma,
                                                 float* __restrict__ out) {
    const size_t i4 = ((size_t)blockIdx.x * 256 + threadIdx.x) * 4;
    const int n = (int)(i4 & (N_ - 1));
    const int b = (int)(i4 >> 20);   // i4/(CQ*N), CQ*N = 2^20
    float4 l1 = *(const float4*)(lpart + (size_t)b * N_ + n);
    float4 l2 = *(const float4*)(lpart + ((size_t)B_ + b) * N_ + n);
    bf16x4 o1 = *(const bf16x4*)(opart + i4);
    bf16x4 o2 = *(const bf16x4*)(opart + (size_t)B_ * CQ_ * N_ + i4);
    float4 q = *(const float4*)(query + i4);
    const float g = gamma[0];
    float4 r;
    r.x = g * ((float)o1[0] + (float)o2[0]) / (l1.x + l2.x) + q.x;
    r.y = g * ((float)o1[1] + (float)o2[1]) / (l1.y + l2.y) + q.y;
    r.z = g * ((float)o1[2] + (float)o2[2]) / (l1.z + l2.z) + q.z;
    r.w = g * ((float)o1[3] + (float)o2[3]) / (l1.w + l2.w) + q.w;
    *(float4*)(out + i4) = r;
}

extern "C" void kernel_launch(void* const* d_in, const int* in_sizes, int n_in,
                              void* d_out, int out_size, void* d_ws, size_t ws_size,
                              hipStream_t stream) {
    const float* query     = (const float*)d_in[0];
    const float* key_value = (const float*)d_in[1];
    const float* Wq = (const float*)d_in[2];
    const float* bq = (const float*)d_in[3];
    const float* Wk = (const float*)d_in[4];
    const float* bk = (const float*)d_in[5];
    const float* Wv = (const float*)d_in[6];
    const float* bv = (const float*)d_in[7];
    const float* gamma = (const float*)d_in[8];
    float* out = (float*)d_out;

    // Workspace layout, TOTAL = 54,788,096 B (< 54,837,248 proven-safe in R2-R7;
    // R8's 55,099,392 overran ws_size and corrupted an adjacent allocation).
    // Weights alias the START of opart: weights are dead after the proj kernels,
    // opart is first written by k_flash (later, same stream) -> safe.
    char* ws = (char*)d_ws;
    bf16*  vbuf  = (bf16*)(ws);              // [8][256][4096]    16,777,216 B
    bf16*  qTb   = (bf16*)(ws + 16777216);   // [8][4096][32]      2,097,152 B
    bf16*  kTb   = (bf16*)(ws + 18874368);   // [8][4096][32]      2,097,152 B
    float* lpart = (float*)(ws + 20971520);  // [2][8][4096]         262,144 B
    bf16*  opart = (bf16*)(ws + 21233664);   // [2][8][256][4096] 33,554,432 B -> ends 54,788,096
    bf16*  wqb   = (bf16*)(ws + 21233664);   // [32][256]  (aliases opart head)
    bf16*  wkb   = (bf16*)(ws + 21250048);   // [32][512]
    bf16*  wvb   = (bf16*)(ws + 21282816);   // [256][512] (ends 21,544,960)

    k_convert_w<<<608, 256, 0, stream>>>(Wq, Wk, Wv, wqb, wkb, wvb);
    k_resize_projkv<<<dim3(64, 8), 256, 0, stream>>>(key_value, wkb, bk, wvb, bv, kTb, vbuf);
    k_proj_q_fused<<<dim3(64, 8), 256, 0, stream>>>(query, wqb, bq, qTb);
    k_flash<<<dim3(8, 64, 2), 256, 0, stream>>>(qTb, kTb, vbuf, opart, lpart);
    k_combine<<<8192, 256, 0, stream>>>(opart, lpart, query, gamma, out);
}